// Round 1
// 60.697 us; speedup vs baseline: 1.1241x; 1.1241x over previous
//
#include <hip/hip_runtime.h>

#define EPSF 1e-5f
#define KSTR 68    // kb LDS row stride (floats)
#define PSTR 260   // kb P row stride

#define FMA4(ACC, ZS, WV) \
    ACC.x = fmaf(ZS, WV.x, ACC.x); ACC.y = fmaf(ZS, WV.y, ACC.y); \
    ACC.z = fmaf(ZS, WV.z, ACC.z); ACC.w = fmaf(ZS, WV.w, ACC.w);

// ---------------------------------------------------------------------------
// KA: patch embed + LN + NF + QKV. 256 blocks x 512 threads, 8 tokens/block.
// Thread (kq=tid>>7, tg=(tid>>6)&1, ln=tid&63): tokens 4tg..4tg+3,
// dims [4ln,4ln+4), k-range [64kq,64kq+64). Weights: global float4/lane.
// z: row-major LDS, float4 broadcast reads cover 4 k per instruction.
// Partials ps[mat][kq][8][256] combined after each phase.
// __launch_bounds__(512,2): LDS caps at 1 block/CU (8 waves = 2/SIMD) anyway;
// pin VGPR budget at 256 so the scheduler can prefetch weight bursts deeply.
// ---------------------------------------------------------------------------
__global__ __launch_bounds__(512, 2) void ka_patch_nf_qkv(
    const float* __restrict__ x,
    const float* __restrict__ Wp, const float* __restrict__ bp,
    const float* __restrict__ ln_g, const float* __restrict__ ln_b,
    const float* __restrict__ Wq, const float* __restrict__ bq,
    const float* __restrict__ Wk, const float* __restrict__ bk,
    const float* __restrict__ Wv, const float* __restrict__ bv,
    float* __restrict__ Qg, float* __restrict__ Kg, float* __restrict__ Vg)
{
    extern __shared__ float sm[];
    float* zr = sm;          // [8][256] patch rows, then z rows
    float* ps = sm + 2048;   // [3][4][8][256] partials (phase0 uses mat slot 0)

    const int tid = threadIdx.x;
    const int kq = tid >> 7, tg = (tid >> 6) & 1, ln = tid & 63;
    const int wave = tid >> 6, lane = tid & 63;
    const int tok0 = blockIdx.x * 8;
    const int tg4 = 4 * tg;

    // ---- stage 8 patches as rows ----
    #pragma unroll
    for (int i = 0; i < 4; ++i) {
        int e = tid + 512 * i;
        int t = e >> 8, dd = e & 255;
        int tk = tok0 + t, b = tk >> 8, n = tk & 255;
        int ph = n >> 4, pw = n & 15, p = dd >> 4, q = dd & 15;
        zr[t * 256 + dd] = x[b * 65536 + (ph * 16 + p) * 256 + pw * 16 + q];
    }
    __syncthreads();

    // ---- phase 0: z = patch @ Wp (8-deep k batches) ----
    {
        const float* wr = Wp + kq * 16384 + 4 * ln;
        const float* zb = zr + tg4 * 256 + kq * 64;
        float4 a0 = make_float4(0.f,0.f,0.f,0.f), a1 = a0, a2 = a0, a3 = a0;
        #pragma unroll
        for (int kk = 0; kk < 64; kk += 8) {
            float4 w0 = *(const float4*)(wr + (kk + 0) * 256);
            float4 w1 = *(const float4*)(wr + (kk + 1) * 256);
            float4 w2 = *(const float4*)(wr + (kk + 2) * 256);
            float4 w3 = *(const float4*)(wr + (kk + 3) * 256);
            float4 w4 = *(const float4*)(wr + (kk + 4) * 256);
            float4 w5 = *(const float4*)(wr + (kk + 5) * 256);
            float4 w6 = *(const float4*)(wr + (kk + 6) * 256);
            float4 w7 = *(const float4*)(wr + (kk + 7) * 256);
            float4 zA0 = *(const float4*)(zb + 0 * 256 + kk);
            float4 zA1 = *(const float4*)(zb + 0 * 256 + kk + 4);
            float4 zB0 = *(const float4*)(zb + 1 * 256 + kk);
            float4 zB1 = *(const float4*)(zb + 1 * 256 + kk + 4);
            float4 zC0 = *(const float4*)(zb + 2 * 256 + kk);
            float4 zC1 = *(const float4*)(zb + 2 * 256 + kk + 4);
            float4 zD0 = *(const float4*)(zb + 3 * 256 + kk);
            float4 zD1 = *(const float4*)(zb + 3 * 256 + kk + 4);
            FMA4(a0, zA0.x, w0) FMA4(a0, zA0.y, w1) FMA4(a0, zA0.z, w2) FMA4(a0, zA0.w, w3)
            FMA4(a0, zA1.x, w4) FMA4(a0, zA1.y, w5) FMA4(a0, zA1.z, w6) FMA4(a0, zA1.w, w7)
            FMA4(a1, zB0.x, w0) FMA4(a1, zB0.y, w1) FMA4(a1, zB0.z, w2) FMA4(a1, zB0.w, w3)
            FMA4(a1, zB1.x, w4) FMA4(a1, zB1.y, w5) FMA4(a1, zB1.z, w6) FMA4(a1, zB1.w, w7)
            FMA4(a2, zC0.x, w0) FMA4(a2, zC0.y, w1) FMA4(a2, zC0.z, w2) FMA4(a2, zC0.w, w3)
            FMA4(a2, zC1.x, w4) FMA4(a2, zC1.y, w5) FMA4(a2, zC1.z, w6) FMA4(a2, zC1.w, w7)
            FMA4(a3, zD0.x, w0) FMA4(a3, zD0.y, w1) FMA4(a3, zD0.z, w2) FMA4(a3, zD0.w, w3)
            FMA4(a3, zD1.x, w4) FMA4(a3, zD1.y, w5) FMA4(a3, zD1.z, w6) FMA4(a3, zD1.w, w7)
        }
        float* pp = ps + kq * 2048 + tg4 * 256 + 4 * ln;
        *(float4*)(pp + 0 * 256) = a0;
        *(float4*)(pp + 1 * 256) = a1;
        *(float4*)(pp + 2 * 256) = a2;
        *(float4*)(pp + 3 * 256) = a3;
    }
    __syncthreads();
    // combine z = sum of 4 k-partials + bias -> zr rows
    {
        int e = tid * 4;
        float4 u0 = *(float4*)(ps + e);
        float4 u1 = *(float4*)(ps + 2048 + e);
        float4 u2 = *(float4*)(ps + 4096 + e);
        float4 u3 = *(float4*)(ps + 6144 + e);
        float4 bb = *(const float4*)(bp + (e & 255));
        float4 z;
        z.x = (u0.x + u1.x) + (u2.x + u3.x) + bb.x;
        z.y = (u0.y + u1.y) + (u2.y + u3.y) + bb.y;
        z.z = (u0.z + u1.z) + (u2.z + u3.z) + bb.z;
        z.w = (u0.w + u1.w) + (u2.w + u3.w) + bb.w;
        *(float4*)(zr + e) = z;
    }
    __syncthreads();

    // ---- LN + NF: wave owns token `wave`; in-place on zr rows ----
    {
        float g[4], bb2[4], v[4];
        #pragma unroll
        for (int c = 0; c < 4; ++c) { g[c] = ln_g[lane + 64 * c]; bb2[c] = ln_b[lane + 64 * c]; }
        float s = 0.f, ss = 0.f;
        #pragma unroll
        for (int c = 0; c < 4; ++c) { v[c] = zr[wave * 256 + lane + 64 * c]; s += v[c]; ss += v[c] * v[c]; }
        #pragma unroll
        for (int o = 32; o; o >>= 1) { s += __shfl_xor(s, o); ss += __shfl_xor(ss, o); }
        float mu  = s * (1.f / 256.f);
        float var = ss * (1.f / 256.f) - mu * mu;
        float rs  = rsqrtf(var + EPSF);
        float zn[4]; float s2 = 0.f, ss2 = 0.f;
        #pragma unroll
        for (int c = 0; c < 4; ++c) {
            zn[c] = (v[c] - mu) * rs * g[c] + bb2[c];
            s2 += zn[c]; ss2 += zn[c] * zn[c];
        }
        #pragma unroll
        for (int o = 32; o; o >>= 1) { s2 += __shfl_xor(s2, o); ss2 += __shfl_xor(ss2, o); }
        float mu2  = s2 * (1.f / 256.f);
        float var2 = ss2 * (1.f / 256.f) - mu2 * mu2;
        float as = 0.f;
        #pragma unroll
        for (int c = 0; c < 4; ++c) as += fabsf(zn[c] - mu2);
        #pragma unroll
        for (int o = 32; o; o >>= 1) as += __shfl_xor(as, o);
        float nf = as / (sqrtf(var2 + EPSF) + EPSF);
        float sc = 1.f + nf;
        #pragma unroll
        for (int c = 0; c < 4; ++c) zr[wave * 256 + lane + 64 * c] = zn[c] * sc;
    }
    __syncthreads();

    // ---- phase 1: Q,K,V fused (4-deep k batches; 48 FMA/k/thread) ----
    {
        const float* qr = Wq + kq * 16384 + 4 * ln;
        const float* kr = Wk + kq * 16384 + 4 * ln;
        const float* vr = Wv + kq * 16384 + 4 * ln;
        const float* zb = zr + tg4 * 256 + kq * 64;
        float4 aq0 = make_float4(0.f,0.f,0.f,0.f), aq1 = aq0, aq2 = aq0, aq3 = aq0;
        float4 ak0 = aq0, ak1 = aq0, ak2 = aq0, ak3 = aq0;
        float4 av0 = aq0, av1 = aq0, av2 = aq0, av3 = aq0;
        #pragma unroll
        for (int kk = 0; kk < 64; kk += 4) {
            float4 qw0 = *(const float4*)(qr + (kk + 0) * 256);
            float4 qw1 = *(const float4*)(qr + (kk + 1) * 256);
            float4 qw2 = *(const float4*)(qr + (kk + 2) * 256);
            float4 qw3 = *(const float4*)(qr + (kk + 3) * 256);
            float4 kw0 = *(const float4*)(kr + (kk + 0) * 256);
            float4 kw1 = *(const float4*)(kr + (kk + 1) * 256);
            float4 kw2 = *(const float4*)(kr + (kk + 2) * 256);
            float4 kw3 = *(const float4*)(kr + (kk + 3) * 256);
            float4 vw0 = *(const float4*)(vr + (kk + 0) * 256);
            float4 vw1 = *(const float4*)(vr + (kk + 1) * 256);
            float4 vw2 = *(const float4*)(vr + (kk + 2) * 256);
            float4 vw3 = *(const float4*)(vr + (kk + 3) * 256);
            float4 zA = *(const float4*)(zb + 0 * 256 + kk);
            float4 zB = *(const float4*)(zb + 1 * 256 + kk);
            float4 zC = *(const float4*)(zb + 2 * 256 + kk);
            float4 zD = *(const float4*)(zb + 3 * 256 + kk);
            FMA4(aq0, zA.x, qw0) FMA4(aq0, zA.y, qw1) FMA4(aq0, zA.z, qw2) FMA4(aq0, zA.w, qw3)
            FMA4(ak0, zA.x, kw0) FMA4(ak0, zA.y, kw1) FMA4(ak0, zA.z, kw2) FMA4(ak0, zA.w, kw3)
            FMA4(av0, zA.x, vw0) FMA4(av0, zA.y, vw1) FMA4(av0, zA.z, vw2) FMA4(av0, zA.w, vw3)
            FMA4(aq1, zB.x, qw0) FMA4(aq1, zB.y, qw1) FMA4(aq1, zB.z, qw2) FMA4(aq1, zB.w, qw3)
            FMA4(ak1, zB.x, kw0) FMA4(ak1, zB.y, kw1) FMA4(ak1, zB.z, kw2) FMA4(ak1, zB.w, kw3)
            FMA4(av1, zB.x, vw0) FMA4(av1, zB.y, vw1) FMA4(av1, zB.z, vw2) FMA4(av1, zB.w, vw3)
            FMA4(aq2, zC.x, qw0) FMA4(aq2, zC.y, qw1) FMA4(aq2, zC.z, qw2) FMA4(aq2, zC.w, qw3)
            FMA4(ak2, zC.x, kw0) FMA4(ak2, zC.y, kw1) FMA4(ak2, zC.z, kw2) FMA4(ak2, zC.w, kw3)
            FMA4(av2, zC.x, vw0) FMA4(av2, zC.y, vw1) FMA4(av2, zC.z, vw2) FMA4(av2, zC.w, vw3)
            FMA4(aq3, zD.x, qw0) FMA4(aq3, zD.y, qw1) FMA4(aq3, zD.z, qw2) FMA4(aq3, zD.w, qw3)
            FMA4(ak3, zD.x, kw0) FMA4(ak3, zD.y, kw1) FMA4(ak3, zD.z, kw2) FMA4(ak3, zD.w, kw3)
            FMA4(av3, zD.x, vw0) FMA4(av3, zD.y, vw1) FMA4(av3, zD.z, vw2) FMA4(av3, zD.w, vw3)
        }
        float* pq = ps + kq * 2048 + tg4 * 256 + 4 * ln;
        *(float4*)(pq + 0 * 256) = aq0;
        *(float4*)(pq + 1 * 256) = aq1;
        *(float4*)(pq + 2 * 256) = aq2;
        *(float4*)(pq + 3 * 256) = aq3;
        float* pk = pq + 8192;
        *(float4*)(pk + 0 * 256) = ak0;
        *(float4*)(pk + 1 * 256) = ak1;
        *(float4*)(pk + 2 * 256) = ak2;
        *(float4*)(pk + 3 * 256) = ak3;
        float* pv = pq + 16384;
        *(float4*)(pv + 0 * 256) = av0;
        *(float4*)(pv + 1 * 256) = av1;
        *(float4*)(pv + 2 * 256) = av2;
        *(float4*)(pv + 3 * 256) = av3;
    }
    __syncthreads();

    // ---- combine + bias + write (B,NH,N,DH) ----
    {
        int e = tid * 4, t = e >> 8, d0 = e & 255;
        int tk = tok0 + t, b = tk >> 8, n = tk & 255;
        int h = d0 >> 6, dh = d0 & 63;
        #pragma unroll
        for (int mat = 0; mat < 3; ++mat) {
            const float* pr = ps + mat * 8192;
            float4 u0 = *(float4*)(pr + e);
            float4 u1 = *(float4*)(pr + 2048 + e);
            float4 u2 = *(float4*)(pr + 4096 + e);
            float4 u3 = *(float4*)(pr + 6144 + e);
            const float* bsrc = (mat == 0) ? bq : (mat == 1) ? bk : bv;
            float4 bb = *(const float4*)(bsrc + d0);
            float4 o;
            o.x = (u0.x + u1.x) + (u2.x + u3.x) + bb.x;
            o.y = (u0.y + u1.y) + (u2.y + u3.y) + bb.y;
            o.z = (u0.z + u1.z) + (u2.z + u3.z) + bb.z;
            o.w = (u0.w + u1.w) + (u2.w + u3.w) + bb.w;
            float* gout = ((mat == 0) ? Qg : (mat == 1) ? Kg : Vg)
                        + ((b * 4 + h) * 256 + n) * 64 + dh;
            *(float4*)gout = o;
        }
    }
}

// ---------------------------------------------------------------------------
// KB v2: AG-NFA attention.
//  - 512 threads (was 256): thread = (q=tid>>4 in [0,32), r=tid&15 in [0,16)).
//  - K staged in LDS (KSTR=68 pad: 2-per-bank on the 16-distinct-row reads,
//    free per m136); 4-way same-address lane broadcast on top.
//  - V NOT staged: PV reads V rows straight from global. m is wave-uniform,
//    so each wave-instruction reads one fully-coalesced 256 B V-row segment;
//    same-bh blocks sit on one XCD (blockIdx&7 swizzle) so V is L1/L2-hot.
//  - Q row (64 f) + NF stats entirely in registers: no cross-lane reduction,
//    no qf/qgs/qis LDS.
//  - LDS 149 KB -> 70.7 KB; occupancy 4 -> 8 waves/CU (1 -> 2 per SIMD).
//  - Identical math: s = qk*(1/8 + 2*inv) - q2*inv - k2*inv, inv=1/(e^-nf+1).
// ---------------------------------------------------------------------------
__global__ __launch_bounds__(512, 2) void kb_attn(
    const float* __restrict__ Qg, const float* __restrict__ Kg,
    const float* __restrict__ Vg, float* __restrict__ Og)
{
    extern __shared__ float lds[];
    float* Kl = lds;               // [256][KSTR]
    float* k2 = lds + 256 * KSTR;  // [256]
    float* Pl = lds;               // [32][PSTR] overlay on Kl after QK^T

    const int tid = threadIdx.x;
    const int xcd = blockIdx.x & 7, slot = blockIdx.x >> 3;
    const int bh = xcd * 4 + (slot >> 3);
    const int qt = slot & 7;

    const float* Qb = Qg + (bh * 256 + qt * 32) * 64;
    const float* Kb = Kg + bh * 16384;
    const float* Vb = Vg + bh * 16384;

    const int q = tid >> 4;   // 0..31: query row
    const int r = tid & 15;   // 0..15: m-phase / dim quad

    // ---- stage K -> LDS (fully coalesced: 8 KB per wave-instruction) ----
    {
        const float4* Ks = (const float4*)Kb;
        #pragma unroll
        for (int i = 0; i < 8; ++i) {
            int flat = tid + 512 * i;            // f4 index, 4096 total
            int row = flat >> 4, c4 = flat & 15;
            *(float4*)(Kl + row * KSTR + c4 * 4) = Ks[flat];
        }
    }
    __syncthreads();

    // ---- k2[m] = |K_m|^2 : pair of threads per row ----
    {
        int row = tid >> 1, half = tid & 1;
        const float* kp = Kl + row * KSTR + half * 32;
        float ssq = 0.f;
        #pragma unroll
        for (int c = 0; c < 8; ++c) {
            float4 kv = *(const float4*)(kp + 4 * c);
            ssq += kv.x*kv.x + kv.y*kv.y + kv.z*kv.z + kv.w*kv.w;
        }
        ssq += __shfl_xor(ssq, 1);
        if (half == 0) k2[row] = ssq;
    }

    // ---- Q row in registers + per-row NF stats (thread-local, no shuffles) --
    float4 Qr[16];
    {
        const float4* Qp = (const float4*)(Qb + q * 64);
        #pragma unroll
        for (int c = 0; c < 16; ++c) Qr[c] = Qp[c];
    }
    float fq, gq, iq;
    {
        float s = 0.f, ss = 0.f;
        #pragma unroll
        for (int c = 0; c < 16; ++c) {
            float4 v = Qr[c];
            s  += v.x + v.y + v.z + v.w;
            ss += v.x*v.x + v.y*v.y + v.z*v.z + v.w*v.w;
        }
        float mu = s * (1.f / 64.f);
        float as = 0.f;
        #pragma unroll
        for (int c = 0; c < 16; ++c) {
            float4 v = Qr[c];
            as += fabsf(v.x - mu) + fabsf(v.y - mu)
                + fabsf(v.z - mu) + fabsf(v.w - mu);
        }
        float var = ss * (1.f / 64.f) - mu * mu;
        float sg  = sqrtf(var + EPSF);
        float nf  = as / (sg + EPSF);
        float inv = 1.f / (__expf(-nf) + 1.f);
        fq = 0.125f + 2.f * inv;
        gq = ss * inv;
        iq = inv;
    }
    __syncthreads();   // k2 visible; Kl stable

    // ---- QK^T: scores for m = r + 16j (16 distinct K rows/wave-instr,
    //      4-way lane broadcast, 2-per-bank => conflict-free) ----
    float s_[16];
    #pragma unroll
    for (int j = 0; j < 16; ++j) {
        int m = r + 16 * j;
        const float* kp = Kl + m * KSTR;
        float acc = 0.f;
        #pragma unroll
        for (int c = 0; c < 16; ++c) {
            float4 kv = *(const float4*)(kp + 4 * c);
            acc += Qr[c].x*kv.x + Qr[c].y*kv.y + Qr[c].z*kv.z + Qr[c].w*kv.w;
        }
        s_[j] = acc * fq - gq - k2[m] * iq;
    }

    // ---- softmax over m: 16 local + 16-lane xor reduce ----
    float M = s_[0];
    #pragma unroll
    for (int j = 1; j < 16; ++j) M = fmaxf(M, s_[j]);
    #pragma unroll
    for (int o = 1; o < 16; o <<= 1) M = fmaxf(M, __shfl_xor(M, o));
    float L = 0.f;
    #pragma unroll
    for (int j = 0; j < 16; ++j) { s_[j] = __expf(s_[j] - M); L += s_[j]; }
    #pragma unroll
    for (int o = 1; o < 16; o <<= 1) L += __shfl_xor(L, o);
    float invL = 1.f / L;

    __syncthreads();   // everyone done reading Kl/k2 -> reuse Kl as Pl
    #pragma unroll
    for (int j = 0; j < 16; ++j) Pl[q * PSTR + r + 16 * j] = s_[j] * invL;
    __syncthreads();

    // ---- PV: thread owns d = 4r..4r+4; V rows streamed from global ----
    float4 a0 = make_float4(0.f, 0.f, 0.f, 0.f);
    const float* pq = Pl + q * PSTR;
    #pragma unroll 8
    for (int m = 0; m < 256; ++m) {
        float pw = pq[m];
        float4 v = *(const float4*)(Vb + m * 64 + 4 * r);
        a0.x = fmaf(pw, v.x, a0.x); a0.y = fmaf(pw, v.y, a0.y);
        a0.z = fmaf(pw, v.z, a0.z); a0.w = fmaf(pw, v.w, a0.w);
    }
    {
        int b = bh >> 2, h = bh & 3;
        int n = qt * 32 + q;
        float* op = Og + (b * 256 + n) * 256 + h * 64 + 4 * r;
        *(float4*)op = a0;
    }
}

// ---------------------------------------------------------------------------
// KC: Y = attn_out @ Wo + bo, then LE-fusion. Same GEMM structure as ka.
// 256 blocks x 512 threads, 8 tokens/block.
// ---------------------------------------------------------------------------
__global__ __launch_bounds__(512, 2) void kc_wo_le(
    const float* __restrict__ Og, const float* __restrict__ Wo,
    const float* __restrict__ bo, float* __restrict__ out)
{
    __shared__ __align__(16) float sm[2048 + 8192 + 8];
    float* yr  = sm;          // [8][256] staged O rows, later y rows
    float* ps  = sm + 2048;   // [4][8][256] k-partials
    float* red = sm + 10240;  // [8]

    const int tid = threadIdx.x;
    const int kq = tid >> 7, tg = (tid >> 6) & 1, ln = tid & 63;
    const int wave = tid >> 6, lane = tid & 63;
    const int tok0 = blockIdx.x * 8;
    const int tg4 = 4 * tg;

    *(float4*)(yr + tid * 4) = *(const float4*)(Og + tok0 * 256 + tid * 4);
    __syncthreads();

    {
        const float* wr = Wo + kq * 16384 + 4 * ln;
        const float* zb = yr + tg4 * 256 + kq * 64;
        float4 a0 = make_float4(0.f,0.f,0.f,0.f), a1 = a0, a2 = a0, a3 = a0;
        #pragma unroll
        for (int kk = 0; kk < 64; kk += 8) {
            float4 w0 = *(const float4*)(wr + (kk + 0) * 256);
            float4 w1 = *(const float4*)(wr + (kk + 1) * 256);
            float4 w2 = *(const float4*)(wr + (kk + 2) * 256);
            float4 w3 = *(const float4*)(wr + (kk + 3) * 256);
            float4 w4 = *(const float4*)(wr + (kk + 4) * 256);
            float4 w5 = *(const float4*)(wr + (kk + 5) * 256);
            float4 w6 = *(const float4*)(wr + (kk + 6) * 256);
            float4 w7 = *(const float4*)(wr + (kk + 7) * 256);
            float4 zA0 = *(const float4*)(zb + 0 * 256 + kk);
            float4 zA1 = *(const float4*)(zb + 0 * 256 + kk + 4);
            float4 zB0 = *(const float4*)(zb + 1 * 256 + kk);
            float4 zB1 = *(const float4*)(zb + 1 * 256 + kk + 4);
            float4 zC0 = *(const float4*)(zb + 2 * 256 + kk);
            float4 zC1 = *(const float4*)(zb + 2 * 256 + kk + 4);
            float4 zD0 = *(const float4*)(zb + 3 * 256 + kk);
            float4 zD1 = *(const float4*)(zb + 3 * 256 + kk + 4);
            FMA4(a0, zA0.x, w0) FMA4(a0, zA0.y, w1) FMA4(a0, zA0.z, w2) FMA4(a0, zA0.w, w3)
            FMA4(a0, zA1.x, w4) FMA4(a0, zA1.y, w5) FMA4(a0, zA1.z, w6) FMA4(a0, zA1.w, w7)
            FMA4(a1, zB0.x, w0) FMA4(a1, zB0.y, w1) FMA4(a1, zB0.z, w2) FMA4(a1, zB0.w, w3)
            FMA4(a1, zB1.x, w4) FMA4(a1, zB1.y, w5) FMA4(a1, zB1.z, w6) FMA4(a1, zB1.w, w7)
            FMA4(a2, zC0.x, w0) FMA4(a2, zC0.y, w1) FMA4(a2, zC0.z, w2) FMA4(a2, zC0.w, w3)
            FMA4(a2, zC1.x, w4) FMA4(a2, zC1.y, w5) FMA4(a2, zC1.z, w6) FMA4(a2, zC1.w, w7)
            FMA4(a3, zD0.x, w0) FMA4(a3, zD0.y, w1) FMA4(a3, zD0.z, w2) FMA4(a3, zD0.w, w3)
            FMA4(a3, zD1.x, w4) FMA4(a3, zD1.y, w5) FMA4(a3, zD1.z, w6) FMA4(a3, zD1.w, w7)
        }
        float* pp = ps + kq * 2048 + tg4 * 256 + 4 * ln;
        *(float4*)(pp + 0 * 256) = a0;
        *(float4*)(pp + 1 * 256) = a1;
        *(float4*)(pp + 2 * 256) = a2;
        *(float4*)(pp + 3 * 256) = a3;
    }
    __syncthreads();
    // combine y = sum 4 partials + bias -> yr rows
    {
        int e = tid * 4;
        float4 u0 = *(float4*)(ps + e);
        float4 u1 = *(float4*)(ps + 2048 + e);
        float4 u2 = *(float4*)(ps + 4096 + e);
        float4 u3 = *(float4*)(ps + 6144 + e);
        float4 bb = *(const float4*)(bo + (e & 255));
        float4 y;
        y.x = (u0.x + u1.x) + (u2.x + u3.x) + bb.x;
        y.y = (u0.y + u1.y) + (u2.y + u3.y) + bb.y;
        y.z = (u0.z + u1.z) + (u2.z + u3.z) + bb.z;
        y.w = (u0.w + u1.w) + (u2.w + u3.w) + bb.w;
        *(float4*)(yr + e) = y;
    }
    __syncthreads();
    // per-token ||Y||: wave owns token `wave`
    {
        float ssq = 0.f;
        #pragma unroll
        for (int c = 0; c < 4; ++c) {
            float v = yr[wave * 256 + lane + 64 * c];
            ssq += v * v;
        }
        #pragma unroll
        for (int o = 32; o; o >>= 1) ssq += __shfl_xor(ssq, o);
        if (lane == 0) red[wave] = sqrtf(ssq);
    }
    __syncthreads();
    // LE-fusion
    {
        int g = tid >> 8, d = tid & 255;
        float e0 = red[4 * g], e1 = red[4 * g + 1], e2 = red[4 * g + 2], e3 = red[4 * g + 3];
        float m = fmaxf(fmaxf(e0, e1), fmaxf(e2, e3));
        float x0 = __expf(e0 - m), x1 = __expf(e1 - m), x2 = __expf(e2 - m), x3 = __expf(e3 - m);
        float inv = 1.f / (x0 + x1 + x2 + x3);
        float val = (x0 * yr[(4 * g) * 256 + d] + x1 * yr[(4 * g + 1) * 256 + d]
                   + x2 * yr[(4 * g + 2) * 256 + d] + x3 * yr[(4 * g + 3) * 256 + d]) * inv;
        out[(blockIdx.x * 2 + g) * 256 + d] = val;
    }
}

// ---------------------------------------------------------------------------
extern "C" void kernel_launch(void* const* d_in, const int* in_sizes, int n_in,
                              void* d_out, int out_size, void* d_ws, size_t ws_size,
                              hipStream_t stream) {
    const float* x    = (const float*)d_in[0];
    const float* Wp   = (const float*)d_in[1];
    const float* bp   = (const float*)d_in[2];
    const float* ln_g = (const float*)d_in[3];
    const float* ln_b = (const float*)d_in[4];
    const float* Wq   = (const float*)d_in[5];
    const float* bq   = (const float*)d_in[6];
    const float* Wk   = (const float*)d_in[7];
    const float* bk   = (const float*)d_in[8];
    const float* Wv   = (const float*)d_in[9];
    const float* bv   = (const float*)d_in[10];
    const float* Wo   = (const float*)d_in[11];
    const float* bo   = (const float*)d_in[12];
    float* out = (float*)d_out;

    float* ws = (float*)d_ws;
    const size_t TKD = 2048 * 64 * 4;
    float* Qg = ws;
    float* Kg = ws + TKD;
    float* Vg = ws + 2 * TKD;
    float* Og = ws + 3 * TKD;

    const int ka_lds = (2048 + 3 * 4 * 2048) * 4;   // 106496 B
    const int kb_lds = (256 * KSTR + 256) * 4;      // 70656 B
    (void)hipFuncSetAttribute((const void*)ka_patch_nf_qkv,
                              hipFuncAttributeMaxDynamicSharedMemorySize, ka_lds);
    (void)hipFuncSetAttribute((const void*)kb_attn,
                              hipFuncAttributeMaxDynamicSharedMemorySize, kb_lds);

    ka_patch_nf_qkv<<<256, 512, ka_lds, stream>>>(x, Wp, bp, ln_g, ln_b,
                                                  Wq, bq, Wk, bk, Wv, bv, Qg, Kg, Vg);
    kb_attn<<<256, 512, kb_lds, stream>>>(Qg, Kg, Vg, Og);
    kc_wo_le<<<256, 512, 0, stream>>>(Og, Wo, bo, out);
}